// Round 7
// baseline (1771.297 us; speedup 1.0000x reference)
//
#include <hip/hip_runtime.h>
#include <math.h>

// FNO1d persistent kernel, software grid barrier (R6's cooperative launch was
// refused by the runtime occupancy check: 57.8KB LDS -> 1 block/CU under the
// 64KB-based calc). This version: LDS 31.7KB, VGPR capped 256 -> 2 blocks/CU
// structural co-residency for 512 blocks; barrier = monotonic agent-scope
// atomic counter (zeroed per launch via memset; graph-capture safe).
//
// h lives in registers in "B-fragment" layout with a channel permutation pi
// folded into the weights (Whp pre-permuted in prep): conv C-output packs
// directly into next conv's B-frags with ZERO data movement. h^T for the DFT
// is produced by an identity-MFMA (one-hot E frags) -> Hout LDS -> b128 reads.
// BasF/BasI fragments load straight from global (L1/L2). GELU = tanh form
// (exp+rcp, inf-safe), error <=1.5e-3 vs exact erf.

typedef _Float16 f16;
typedef _Float16 f16x8 __attribute__((ext_vector_type(8)));
typedef float    f32x4 __attribute__((ext_vector_type(4)));
typedef unsigned int u32;
typedef u32 u32x2 __attribute__((ext_vector_type(2)));
typedef u32 u32x4 __attribute__((ext_vector_type(4)));

#define NN 8192
#define HO_S 136   // Hout [o=64][n=128] halfs; 272B rows (16B mult)
#define WS_S 72    // Ws [o=64][s=64]
#define MS_S 40    // Ms2 [o=64][j=32]

__device__ __forceinline__ float gelu_t(float v) {
    // 0.5v(1+tanh(.79788(v+.044715v^3))) = v - v/(exp(y)+1), y=2*.79788*(v+...)
    float v2 = v * v;
    float y  = v * fmaf(v2, 0.0713548162f, 1.5957691216f);
    float e  = __expf(y);
    float r  = __builtin_amdgcn_rcpf(e + 1.0f);
    return fmaf(-v, r, v);   // e=inf -> r=0 -> v; e=0 -> r=1 -> 0
}

// ---------------------------------------------------------------- prep
// basF[k][n]=cos(2pi kn/N), basF[16+k][n]=-sin; basI[n][2k]=cos,[2k+1]=sin.
// Whp = w_w cast fp16 with i-dim permuted by pi (see kernel comments).
__global__ __launch_bounds__(256) void fill_basis(f16* __restrict__ basF,
                                                  f16* __restrict__ basI,
                                                  const float* __restrict__ w_w,
                                                  f16* __restrict__ Whp) {
    int n = blockIdx.x * 256 + threadIdx.x;   // 0..8191
    f16 row[32];
#pragma unroll
    for (int k = 0; k < 16; ++k) {
        float s, c;
        sincospif((float)(k * n) * (1.0f / 4096.0f), &s, &c);
        basF[k * NN + n]        = (f16)c;
        basF[(16 + k) * NN + n] = (f16)(-s);
        row[2 * k]     = (f16)c;
        row[2 * k + 1] = (f16)s;
    }
#pragma unroll
    for (int qq = 0; qq < 4; ++qq) *(f16x8*)&basI[n * 32 + 8 * qq] = *(f16x8*)&row[8 * qq];
#pragma unroll
    for (int rep = 0; rep < 2; ++rep) {
        int idx = n + rep * 8192;             // 16384 = 4 layers * 64o * 64s
        int l = idx >> 12, o = (idx >> 6) & 63, s = idx & 63;
        int ks = s >> 5, qq = (s >> 3) & 3, tt = (s >> 1) & 3, e = s & 1;
        int i = 32 * (tt >> 1) + 16 * ks + 4 * qq + 2 * (tt & 1) + e;   // pi(s)
        Whp[idx] = (f16)w_w[(l * 64 + o) * 64 + i];
    }
}

// ---------------------------------------------------------------- main
__global__ __launch_bounds__(256, 2) void fno_all(
    const float* __restrict__ x, const float* __restrict__ p_w,
    const float* __restrict__ p_b, const f16* __restrict__ Whp,
    const float* __restrict__ w_b, const float* __restrict__ sc_wr,
    const float* __restrict__ sc_wi, const float* __restrict__ q_w,
    const float* __restrict__ q_b, const f16* __restrict__ basF_g,
    const f16* __restrict__ basI_g, float* __restrict__ S,
    f16* __restrict__ Mph, float* __restrict__ out,
    unsigned int* __restrict__ cnt) {
    __shared__ __align__(16) char poolA[64 * HO_S * 2];   // Hout / modemix Ss
    __shared__ __align__(16) f16 Ws[64 * WS_S];
    __shared__ __align__(16) f16 Ms2[64 * MS_S];
    f16* Hout = (f16*)poolA;
    float* Ss = (float*)poolA;

    const int t = threadIdx.x, g = blockIdx.x;
    const int b = g >> 3, j8 = g & 7;
    const int lane = t & 63, wv = t >> 6, q = lane >> 4, l15 = lane & 15;

    // one-hot E frags for the identity-MFMA transpose
    f16x8 Elo = {0, 0, 0, 0, 0, 0, 0, 0};
    f16x8 Ehi = {0, 0, 0, 0, 0, 0, 0, 0};
    {
        int d = l15 - 4 * q;
#pragma unroll
        for (int j = 0; j < 4; ++j) {
            if (j == d) { Elo[j] = (f16)1; Ehi[j + 4] = (f16)1; }
        }
    }

    unsigned bt = 0;
    auto gbar = [&]() {
        bt += 512;
        __threadfence();
        __syncthreads();
        if (t == 0) {
            __hip_atomic_fetch_add(cnt, 1u, __ATOMIC_ACQ_REL, __HIP_MEMORY_SCOPE_AGENT);
            while (__hip_atomic_load(cnt, __ATOMIC_ACQUIRE, __HIP_MEMORY_SCOPE_AGENT) < bt)
                __builtin_amdgcn_s_sleep(2);
        }
        __syncthreads();
        __threadfence();
    };

    u32 hreg[8][2][8];   // [unit][mtl][ks*4+slot] packed f16 pairs

    // transpose (identity MFMA) -> Hout[o][n], then DFT accumulate
    auto unit_tail = [&](int u, f32x4* sacc) {
        int nb = ((j8 << 3) + u) << 7;
        __syncthreads();   // prior unit's Hout reads complete
#pragma unroll
        for (int mtl = 0; mtl < 2; ++mtl) {
            u32x4 t0 = {hreg[u][mtl][0], hreg[u][mtl][1], hreg[u][mtl][2], hreg[u][mtl][3]};
            u32x4 t1 = {hreg[u][mtl][4], hreg[u][mtl][5], hreg[u][mtl][6], hreg[u][mtl][7]};
            f16x8 A0 = __builtin_bit_cast(f16x8, t0);
            f16x8 A1 = __builtin_bit_cast(f16x8, t1);
#pragma unroll
            for (int f = 0; f < 4; ++f) {
                f32x4 d2 = __builtin_amdgcn_mfma_f32_16x16x32_f16(
                    (f & 1) ? A1 : A0, (f >> 1) ? Ehi : Elo,
                    (f32x4){0.f, 0.f, 0.f, 0.f}, 0, 0, 0);
                u32 p0 = __builtin_bit_cast(u32, __builtin_amdgcn_cvt_pkrtz(d2[0], d2[1]));
                u32 p1 = __builtin_bit_cast(u32, __builtin_amdgcn_cvt_pkrtz(d2[2], d2[3]));
                u32x2 pr = {p0, p1};
                *(u32x2*)&Hout[(16 * f + l15) * HO_S + 16 * (2 * wv + mtl) + 4 * q] = pr;
            }
        }
        __syncthreads();
#pragma unroll
        for (int ksn = 0; ksn < 4; ++ksn) {
            f16x8 bh = *(const f16x8*)&Hout[(wv * 16 + l15) * HO_S + ksn * 32 + q * 8];
#pragma unroll
            for (int mt = 0; mt < 2; ++mt) {
                f16x8 af = *(const f16x8*)&basF_g[(mt * 16 + l15) * NN + nb + ksn * 32 + q * 8];
                sacc[mt] = __builtin_amdgcn_mfma_f32_16x16x32_f16(af, bh, sacc[mt], 0, 0, 0);
            }
        }
    };

    auto flushS = [&](f32x4* sacc) {
#pragma unroll
        for (int mt = 0; mt < 2; ++mt)
#pragma unroll
            for (int r = 0; r < 4; ++r)
                atomicAdd(&S[(b * 32 + mt * 16 + 4 * q + r) * 64 + wv * 16 + l15],
                          sacc[mt][r]);
    };

    // ================= lift into hreg (pi-packed B layout) =================
    {
        float pwA[16], pwB[16], pbv[16];
#pragma unroll
        for (int f = 0; f < 4; ++f)
#pragma unroll
            for (int g2 = 0; g2 < 2; ++g2)
#pragma unroll
                for (int e = 0; e < 2; ++e) {
                    int c = f * 4 + g2 * 2 + e;
                    int i = 16 * f + 4 * q + 2 * g2 + e;
                    pwA[c] = p_w[2 * i]; pwB[c] = p_w[2 * i + 1]; pbv[c] = p_b[i];
                }
#pragma unroll
        for (int u = 0; u < 8; ++u) {
            int nb = ((j8 << 3) + u) << 7;
#pragma unroll
            for (int mtl = 0; mtl < 2; ++mtl) {
                int n = nb + 16 * (2 * wv + mtl) + l15;
                float xv = x[(b << 13) + n];
                float gr = (float)n * (1.0f / 8191.0f);
#pragma unroll
                for (int f = 0; f < 4; ++f)
#pragma unroll
                    for (int g2 = 0; g2 < 2; ++g2) {
                        int c = f * 4 + g2 * 2;
                        float v0 = fmaf(pwA[c], xv, fmaf(pwB[c], gr, pbv[c]));
                        float v1 = fmaf(pwA[c + 1], xv, fmaf(pwB[c + 1], gr, pbv[c + 1]));
                        hreg[u][mtl][(f & 1) * 4 + 2 * (f >> 1) + g2] =
                            __builtin_bit_cast(u32, __builtin_amdgcn_cvt_pkrtz(v0, v1));
                    }
            }
        }
    }
    {
        f32x4 sacc[2] = {{0.f,0.f,0.f,0.f},{0.f,0.f,0.f,0.f}};
#pragma unroll
        for (int u = 0; u < 8; ++u) unit_tail(u, sacc);
        flushS(sacc);
    }
    gbar();   // S(h1) complete

    // ================= layers =================
    for (int l = 0; l < 4; ++l) {
        // stage Ws (pre-permuted weights)
#pragma unroll
        for (int rr = 0; rr < 2; ++rr) {
            int v = t + 256 * rr;
            int o = v >> 3, c = (v & 7) * 8;
            *(f16x8*)&Ws[o * WS_S + c] = *(const f16x8*)&Whp[l * 4096 + o * 64 + c];
        }
        if (j8 == 0) {
            // ---- modemix for this b (agent-scope loads/stores for XCD coherence)
#pragma unroll
            for (int r = 0; r < 8; ++r) {
                int v = t + 256 * r;
                Ss[(v >> 6) * 66 + (v & 63)] =
                    __hip_atomic_load(&S[b * 2048 + v], __ATOMIC_RELAXED,
                                      __HIP_MEMORY_SCOPE_AGENT);
            }
            __syncthreads();
            const float* wr = sc_wr + l * 65536;
            const float* wi = sc_wi + l * 65536;
            u32* MphU = (u32*)Mph;
#pragma unroll
            for (int it = 0; it < 4; ++it) {
                int p = it * 256 + t;     // o*16+k
                int o = p >> 4, k = p & 15;
                float ar = 0.f, ai = 0.f;
#pragma unroll 4
                for (int i = 0; i < 64; ++i) {
                    float sr = Ss[k * 66 + i], si = Ss[(16 + k) * 66 + i];
                    float wrv = wr[(i * 64 + o) * 16 + k];
                    float wiv = wi[(i * 64 + o) * 16 + k];
                    ar += sr * wrv - si * wiv;
                    ai += sr * wiv + si * wrv;
                }
                float sc = (k == 0 ? 1.0f : 2.0f) * (1.0f / 8192.0f);
                u32 pk = __builtin_bit_cast(u32,
                    __builtin_amdgcn_cvt_pkrtz(sc * ar, -sc * ai));
                __hip_atomic_store(&MphU[b * 1024 + o * 16 + k], pk,
                                   __ATOMIC_RELAXED, __HIP_MEMORY_SCOPE_AGENT);
            }
#pragma unroll
            for (int r = 0; r < 8; ++r)
                __hip_atomic_store(&S[b * 2048 + t + 256 * r], 0.f,
                                   __ATOMIC_RELAXED, __HIP_MEMORY_SCOPE_AGENT);
        }
        gbar();   // Mph ready, S zeroed

        // stage Ms2 from Mph
        {
            u32* Ms2U = (u32*)Ms2;
            const u32* MphU = (const u32*)Mph;
#pragma unroll
            for (int ii = 0; ii < 4; ++ii) {
                int idx = ii * 256 + t;
                int o = idx >> 4, kp = idx & 15;
                u32 val = __hip_atomic_load(&MphU[b * 1024 + idx], __ATOMIC_RELAXED,
                                            __HIP_MEMORY_SCOPE_AGENT);
                Ms2U[o * 20 + kp] = val;
            }
        }
        __syncthreads();

        float bvv[16];
#pragma unroll
        for (int ct = 0; ct < 4; ++ct)
#pragma unroll
            for (int r = 0; r < 4; ++r)
                bvv[ct * 4 + r] = w_b[l * 64 + ct * 16 + 4 * q + r];
        float qwv[16], qb = 0.f;
        if (l == 3) {
#pragma unroll
            for (int ct = 0; ct < 4; ++ct)
#pragma unroll
                for (int r = 0; r < 4; ++r)
                    qwv[ct * 4 + r] = q_w[ct * 16 + 4 * q + r];
            qb = q_b[0];
        }

        f32x4 sacc[2] = {{0.f,0.f,0.f,0.f},{0.f,0.f,0.f,0.f}};
#pragma unroll
        for (int u = 0; u < 8; ++u) {
            int nb = ((j8 << 3) + u) << 7;
            f16x8 Aw0[4], Aw1[4], Am[4];
#pragma unroll
            for (int ct = 0; ct < 4; ++ct) {
                Aw0[ct] = *(const f16x8*)&Ws[(ct * 16 + l15) * WS_S + q * 8];
                Aw1[ct] = *(const f16x8*)&Ws[(ct * 16 + l15) * WS_S + 32 + q * 8];
                Am[ct]  = *(const f16x8*)&Ms2[(ct * 16 + l15) * MS_S + q * 8];
            }
            f32x4 acc[4][2];
#pragma unroll
            for (int ct = 0; ct < 4; ++ct)
#pragma unroll
                for (int m = 0; m < 2; ++m) acc[ct][m] = (f32x4){0.f, 0.f, 0.f, 0.f};
#pragma unroll
            for (int mtl = 0; mtl < 2; ++mtl) {
                u32x4 tb0 = {hreg[u][mtl][0], hreg[u][mtl][1], hreg[u][mtl][2], hreg[u][mtl][3]};
                u32x4 tb1 = {hreg[u][mtl][4], hreg[u][mtl][5], hreg[u][mtl][6], hreg[u][mtl][7]};
                f16x8 B0 = __builtin_bit_cast(f16x8, tb0);
                f16x8 B1 = __builtin_bit_cast(f16x8, tb1);
                f16x8 Bi = *(const f16x8*)&basI_g[(nb + 16 * (2 * wv + mtl) + l15) * 32 + q * 8];
#pragma unroll
                for (int ct = 0; ct < 4; ++ct) {
                    acc[ct][mtl] = __builtin_amdgcn_mfma_f32_16x16x32_f16(Aw0[ct], B0, acc[ct][mtl], 0, 0, 0);
                    acc[ct][mtl] = __builtin_amdgcn_mfma_f32_16x16x32_f16(Aw1[ct], B1, acc[ct][mtl], 0, 0, 0);
                    acc[ct][mtl] = __builtin_amdgcn_mfma_f32_16x16x32_f16(Am[ct],  Bi, acc[ct][mtl], 0, 0, 0);
                }
            }
            if (l < 3) {
#pragma unroll
                for (int mtl = 0; mtl < 2; ++mtl)
#pragma unroll
                    for (int ct = 0; ct < 4; ++ct) {
                        float g0 = gelu_t(acc[ct][mtl][0] + bvv[ct * 4 + 0]);
                        float g1 = gelu_t(acc[ct][mtl][1] + bvv[ct * 4 + 1]);
                        float g2 = gelu_t(acc[ct][mtl][2] + bvv[ct * 4 + 2]);
                        float g3 = gelu_t(acc[ct][mtl][3] + bvv[ct * 4 + 3]);
                        hreg[u][mtl][(ct & 1) * 4 + 2 * (ct >> 1) + 0] =
                            __builtin_bit_cast(u32, __builtin_amdgcn_cvt_pkrtz(g0, g1));
                        hreg[u][mtl][(ct & 1) * 4 + 2 * (ct >> 1) + 1] =
                            __builtin_bit_cast(u32, __builtin_amdgcn_cvt_pkrtz(g2, g3));
                    }
                unit_tail(u, sacc);
            } else {
#pragma unroll
                for (int mtl = 0; mtl < 2; ++mtl) {
                    float partial = 0.f;
#pragma unroll
                    for (int ct = 0; ct < 4; ++ct)
#pragma unroll
                        for (int r = 0; r < 4; ++r)
                            partial += qwv[ct * 4 + r] *
                                       gelu_t(acc[ct][mtl][r] + bvv[ct * 4 + r]);
                    partial += __shfl_xor(partial, 16);
                    partial += __shfl_xor(partial, 32);
                    if (q == 0)
                        out[(b << 13) + nb + 16 * (2 * wv + mtl) + l15] = partial + qb;
                }
            }
        }
        if (l < 3) { flushS(sacc); gbar(); }
    }
}

// ---------------------------------------------------------------- launch
extern "C" void kernel_launch(void* const* d_in, const int* in_sizes, int n_in,
                              void* d_out, int out_size, void* d_ws, size_t ws_size,
                              hipStream_t stream) {
    const float* x     = (const float*)d_in[0];
    const float* p_w   = (const float*)d_in[1];
    const float* p_b   = (const float*)d_in[2];
    const float* sc_wr = (const float*)d_in[3];
    const float* sc_wi = (const float*)d_in[4];
    const float* w_w   = (const float*)d_in[5];
    const float* w_b   = (const float*)d_in[6];
    const float* q_w   = (const float*)d_in[7];
    const float* q_b   = (const float*)d_in[8];
    float* out = (float*)d_out;

    char* ws = (char*)d_ws;
    float* S    = (float*)ws;                      // 524,288 B
    f16*   Mph  = (f16*)(ws + 524288ull);          // 262,144 B
    f16*   basF = (f16*)(ws + 786432ull);          // 524,288 B
    f16*   basI = (f16*)(ws + 1310720ull);         // 524,288 B
    f16*   Whp  = (f16*)(ws + 1835008ull);         // 32,768 B
    unsigned int* cnt = (unsigned int*)(ws + 1867776ull);   // 128 B

    hipLaunchKernelGGL(fill_basis, dim3(NN / 256), dim3(256), 0, stream,
                       basF, basI, w_w, Whp);
    (void)hipMemsetAsync(S, 0, 524288, stream);
    (void)hipMemsetAsync(cnt, 0, 128, stream);
    hipLaunchKernelGGL(fno_all, dim3(512), dim3(256), 0, stream,
                       x, p_w, p_b, Whp, w_b, sc_wr, sc_wi, q_w, q_b,
                       basF, basI, S, Mph, out, cnt);
}

// Round 8
// 1537.589 us; speedup vs baseline: 1.1520x; 1.1520x over previous
//
#include <hip/hip_runtime.h>
#include <math.h>

// FNO1d persistent kernel, R8: R7's verified algorithm (pi-permuted B-layout h,
// identity-MFMA transpose, software grid barrier) with the scratch spill fixed.
// R7 failure: lambda by-ref captures blocked SROA -> hreg[8][2][8] lived in
// scratch (VGPR_Count=128, 500MB scratch traffic, 1771us). R8: macros instead
// of lambdas; h split 6 units in registers (96 VGPRs) + 2 units in LDS (32KB,
// lane-stride-1, private per thread). LDS ~65KB, VGPR ~220 -> 2 blocks/CU
// structural co-residency for 512 blocks. Barrier spin is bounded (fails loud,
// never hangs).

typedef _Float16 f16;
typedef _Float16 f16x8 __attribute__((ext_vector_type(8)));
typedef float    f32x4 __attribute__((ext_vector_type(4)));
typedef unsigned int u32;
typedef u32 u32x2 __attribute__((ext_vector_type(2)));
typedef u32 u32x4 __attribute__((ext_vector_type(4)));

#define NN 8192
#define HO_S 136   // Hout [o=64][n=128] halfs
#define WS_S 72    // Ws [o=64][s=64]
#define MS_S 40    // Ms2 [o=64][j=32]
#define NREG 6     // h units in registers
#define NLDS 2     // h units in LDS

__device__ __forceinline__ float gelu_t(float v) {
    float v2 = v * v;
    float y  = v * fmaf(v2, 0.0713548162f, 1.5957691216f);
    float e  = __expf(y);
    float r  = __builtin_amdgcn_rcpf(e + 1.0f);
    return fmaf(-v, r, v);   // inf-safe tanh-GELU
}

// ---------------------------------------------------------------- prep
__global__ __launch_bounds__(256) void fill_basis(f16* __restrict__ basF,
                                                  f16* __restrict__ basI,
                                                  const float* __restrict__ w_w,
                                                  f16* __restrict__ Whp) {
    int n = blockIdx.x * 256 + threadIdx.x;
    f16 row[32];
#pragma unroll
    for (int k = 0; k < 16; ++k) {
        float s, c;
        sincospif((float)(k * n) * (1.0f / 4096.0f), &s, &c);
        basF[k * NN + n]        = (f16)c;
        basF[(16 + k) * NN + n] = (f16)(-s);
        row[2 * k]     = (f16)c;
        row[2 * k + 1] = (f16)s;
    }
#pragma unroll
    for (int qq = 0; qq < 4; ++qq) *(f16x8*)&basI[n * 32 + 8 * qq] = *(f16x8*)&row[8 * qq];
#pragma unroll
    for (int rep = 0; rep < 2; ++rep) {
        int idx = n + rep * 8192;
        int l = idx >> 12, o = (idx >> 6) & 63, s = idx & 63;
        int ks = s >> 5, qq = (s >> 3) & 3, tt = (s >> 1) & 3, e = s & 1;
        int i = 32 * (tt >> 1) + 16 * ks + 4 * qq + 2 * (tt & 1) + e;   // pi(s)
        Whp[idx] = (f16)w_w[(l * 64 + o) * 64 + i];
    }
}

// ---- h state access (u must be a compile-time constant via unrolled loops)
#define HLOAD(u, mtl, B0, B1) do {                                            \
    if ((u) < NREG) {                                                         \
        u32x4 t0_ = {hreg[(u)][(mtl)][0], hreg[(u)][(mtl)][1],                \
                     hreg[(u)][(mtl)][2], hreg[(u)][(mtl)][3]};               \
        u32x4 t1_ = {hreg[(u)][(mtl)][4], hreg[(u)][(mtl)][5],                \
                     hreg[(u)][(mtl)][6], hreg[(u)][(mtl)][7]};               \
        (B0) = __builtin_bit_cast(f16x8, t0_);                                \
        (B1) = __builtin_bit_cast(f16x8, t1_);                                \
    } else {                                                                  \
        u32 w_[8];                                                            \
        _Pragma("unroll")                                                     \
        for (int s_ = 0; s_ < 8; ++s_)                                        \
            w_[s_] = hlds[(((mtl) * 8 + s_) * NLDS + (u) - NREG) * 256 + t];  \
        u32x4 t0_ = {w_[0], w_[1], w_[2], w_[3]};                             \
        u32x4 t1_ = {w_[4], w_[5], w_[6], w_[7]};                             \
        (B0) = __builtin_bit_cast(f16x8, t0_);                                \
        (B1) = __builtin_bit_cast(f16x8, t1_);                                \
    }                                                                         \
} while (0)

#define HSTORE1(u, mtl, slot, val) do {                                       \
    if ((u) < NREG) hreg[(u)][(mtl)][(slot)] = (val);                         \
    else hlds[(((mtl) * 8 + (slot)) * NLDS + (u) - NREG) * 256 + t] = (val);  \
} while (0)

// identity-MFMA transpose -> Hout, then DFT accumulate (verified in R7)
#define UNIT_TAIL(u) do {                                                     \
    int nb_ = ((j8 << 3) + (u)) << 7;                                         \
    __syncthreads();                                                          \
    _Pragma("unroll")                                                         \
    for (int mtl_ = 0; mtl_ < 2; ++mtl_) {                                    \
        f16x8 A0_, A1_;                                                       \
        HLOAD((u), mtl_, A0_, A1_);                                           \
        _Pragma("unroll")                                                     \
        for (int f_ = 0; f_ < 4; ++f_) {                                      \
            f32x4 d2_ = __builtin_amdgcn_mfma_f32_16x16x32_f16(               \
                (f_ & 1) ? A1_ : A0_, (f_ >> 1) ? Ehi : Elo,                  \
                (f32x4){0.f, 0.f, 0.f, 0.f}, 0, 0, 0);                        \
            u32 p0_ = __builtin_bit_cast(u32,                                 \
                __builtin_amdgcn_cvt_pkrtz(d2_[0], d2_[1]));                  \
            u32 p1_ = __builtin_bit_cast(u32,                                 \
                __builtin_amdgcn_cvt_pkrtz(d2_[2], d2_[3]));                  \
            u32x2 pr_ = {p0_, p1_};                                           \
            *(u32x2*)&Hout[(16 * f_ + l15) * HO_S + 16 * (2 * wv + mtl_) + 4 * q] = pr_; \
        }                                                                     \
    }                                                                         \
    __syncthreads();                                                          \
    _Pragma("unroll")                                                         \
    for (int ksn_ = 0; ksn_ < 4; ++ksn_) {                                    \
        f16x8 bh_ = *(const f16x8*)&Hout[(wv * 16 + l15) * HO_S + ksn_ * 32 + q * 8]; \
        _Pragma("unroll")                                                     \
        for (int mt_ = 0; mt_ < 2; ++mt_) {                                   \
            f16x8 af_ = *(const f16x8*)&basF_g[(mt_ * 16 + l15) * NN + nb_ + ksn_ * 32 + q * 8]; \
            sacc[mt_] = __builtin_amdgcn_mfma_f32_16x16x32_f16(af_, bh_, sacc[mt_], 0, 0, 0); \
        }                                                                     \
    }                                                                         \
} while (0)

// ---------------------------------------------------------------- main
__global__ __launch_bounds__(256, 2) void fno_all(
    const float* __restrict__ x, const float* __restrict__ p_w,
    const float* __restrict__ p_b, const f16* __restrict__ Whp,
    const float* __restrict__ w_b, const float* __restrict__ sc_wr,
    const float* __restrict__ sc_wi, const float* __restrict__ q_w,
    const float* __restrict__ q_b, const f16* __restrict__ basF_g,
    const f16* __restrict__ basI_g, float* __restrict__ S,
    f16* __restrict__ Mph, float* __restrict__ out,
    unsigned int* __restrict__ cnt) {
    __shared__ __align__(16) char poolA[64 * HO_S * 2];   // Hout / modemix Ss
    __shared__ __align__(16) f16 Ws[64 * WS_S];
    __shared__ __align__(16) f16 Ms2[64 * MS_S];
    __shared__ u32 hlds[NLDS * 256 * 16];                 // 32768 B
    __shared__ float bls[64];
    __shared__ float qls[64];
    f16* Hout = (f16*)poolA;
    float* Ss = (float*)poolA;

    const int t = threadIdx.x, g = blockIdx.x;
    const int b = g >> 3, j8 = g & 7;
    const int lane = t & 63, wv = t >> 6, q = lane >> 4, l15 = lane & 15;

    f16x8 Elo = {0, 0, 0, 0, 0, 0, 0, 0};
    f16x8 Ehi = {0, 0, 0, 0, 0, 0, 0, 0};
    {
        int d = l15 - 4 * q;
#pragma unroll
        for (int j = 0; j < 4; ++j)
            if (j == d) { Elo[j] = (f16)1; Ehi[j + 4] = (f16)1; }
    }

    if (t < 64) qls[t] = q_w[t];
    float qb = q_b[0];

    u32 hreg[NREG][2][8];
    unsigned bt = 0;

    // ================= lift into h (pi-packed B layout) =================
    {
        float pwA[16], pwB[16], pbv[16];
#pragma unroll
        for (int f = 0; f < 4; ++f)
#pragma unroll
            for (int g2 = 0; g2 < 2; ++g2)
#pragma unroll
                for (int e = 0; e < 2; ++e) {
                    int c = f * 4 + g2 * 2 + e;
                    int i = 16 * f + 4 * q + 2 * g2 + e;
                    pwA[c] = p_w[2 * i]; pwB[c] = p_w[2 * i + 1]; pbv[c] = p_b[i];
                }
#pragma unroll
        for (int u = 0; u < 8; ++u) {
            int nb = ((j8 << 3) + u) << 7;
#pragma unroll
            for (int mtl = 0; mtl < 2; ++mtl) {
                int n = nb + 16 * (2 * wv + mtl) + l15;
                float xv = x[(b << 13) + n];
                float gr = (float)n * (1.0f / 8191.0f);
#pragma unroll
                for (int f = 0; f < 4; ++f)
#pragma unroll
                    for (int g2 = 0; g2 < 2; ++g2) {
                        int c = f * 4 + g2 * 2;
                        float v0 = fmaf(pwA[c], xv, fmaf(pwB[c], gr, pbv[c]));
                        float v1 = fmaf(pwA[c + 1], xv, fmaf(pwB[c + 1], gr, pbv[c + 1]));
                        u32 pk = __builtin_bit_cast(u32, __builtin_amdgcn_cvt_pkrtz(v0, v1));
                        HSTORE1(u, mtl, (f & 1) * 4 + 2 * (f >> 1) + g2, pk);
                    }
            }
        }
    }
    {
        f32x4 sacc[2] = {{0.f,0.f,0.f,0.f},{0.f,0.f,0.f,0.f}};
#pragma unroll
        for (int u = 0; u < 8; ++u) UNIT_TAIL(u);
#pragma unroll
        for (int mt = 0; mt < 2; ++mt)
#pragma unroll
            for (int r = 0; r < 4; ++r)
                atomicAdd(&S[(b * 32 + mt * 16 + 4 * q + r) * 64 + wv * 16 + l15],
                          sacc[mt][r]);
    }
    // ---- grid barrier
    {
        bt += 512;
        __threadfence();
        __syncthreads();
        if (t == 0) {
            __hip_atomic_fetch_add(cnt, 1u, __ATOMIC_ACQ_REL, __HIP_MEMORY_SCOPE_AGENT);
            long it = 0;
            while (__hip_atomic_load(cnt, __ATOMIC_ACQUIRE, __HIP_MEMORY_SCOPE_AGENT) < bt
                   && it < (1L << 23)) { __builtin_amdgcn_s_sleep(2); ++it; }
        }
        __syncthreads();
        __threadfence();
    }

    // ================= layers =================
    for (int l = 0; l < 4; ++l) {
        // stage Ws (pre-permuted)
#pragma unroll
        for (int rr = 0; rr < 2; ++rr) {
            int v = t + 256 * rr;
            int o = v >> 3, c = (v & 7) * 8;
            *(f16x8*)&Ws[o * WS_S + c] = *(const f16x8*)&Whp[l * 4096 + o * 64 + c];
        }
        if (t < 64) bls[t] = w_b[l * 64 + t];
        if (j8 == 0) {
            // modemix for this b
#pragma unroll
            for (int r = 0; r < 8; ++r) {
                int v = t + 256 * r;
                Ss[(v >> 6) * 66 + (v & 63)] =
                    __hip_atomic_load(&S[b * 2048 + v], __ATOMIC_RELAXED,
                                      __HIP_MEMORY_SCOPE_AGENT);
            }
            __syncthreads();
            const float* wr = sc_wr + l * 65536;
            const float* wi = sc_wi + l * 65536;
            u32* MphU = (u32*)Mph;
#pragma unroll
            for (int it2 = 0; it2 < 4; ++it2) {
                int p = it2 * 256 + t;     // o*16+k
                int o = p >> 4, k = p & 15;
                float ar = 0.f, ai = 0.f;
#pragma unroll 4
                for (int i = 0; i < 64; ++i) {
                    float sr = Ss[k * 66 + i], si = Ss[(16 + k) * 66 + i];
                    float wrv = wr[(i * 64 + o) * 16 + k];
                    float wiv = wi[(i * 64 + o) * 16 + k];
                    ar += sr * wrv - si * wiv;
                    ai += sr * wiv + si * wrv;
                }
                float sc = (k == 0 ? 1.0f : 2.0f) * (1.0f / 8192.0f);
                u32 pk = __builtin_bit_cast(u32,
                    __builtin_amdgcn_cvt_pkrtz(sc * ar, -sc * ai));
                __hip_atomic_store(&MphU[b * 1024 + o * 16 + k], pk,
                                   __ATOMIC_RELAXED, __HIP_MEMORY_SCOPE_AGENT);
            }
#pragma unroll
            for (int r = 0; r < 8; ++r)
                __hip_atomic_store(&S[b * 2048 + t + 256 * r], 0.f,
                                   __ATOMIC_RELAXED, __HIP_MEMORY_SCOPE_AGENT);
        }
        // ---- grid barrier (Mph ready, S zeroed)
        {
            bt += 512;
            __threadfence();
            __syncthreads();
            if (t == 0) {
                __hip_atomic_fetch_add(cnt, 1u, __ATOMIC_ACQ_REL, __HIP_MEMORY_SCOPE_AGENT);
                long it = 0;
                while (__hip_atomic_load(cnt, __ATOMIC_ACQUIRE, __HIP_MEMORY_SCOPE_AGENT) < bt
                       && it < (1L << 23)) { __builtin_amdgcn_s_sleep(2); ++it; }
            }
            __syncthreads();
            __threadfence();
        }
        // stage Ms2
        {
            u32* Ms2U = (u32*)Ms2;
            const u32* MphU = (const u32*)Mph;
#pragma unroll
            for (int ii = 0; ii < 4; ++ii) {
                int idx = ii * 256 + t;
                int o = idx >> 4, kp = idx & 15;
                u32 val = __hip_atomic_load(&MphU[b * 1024 + idx], __ATOMIC_RELAXED,
                                            __HIP_MEMORY_SCOPE_AGENT);
                Ms2U[o * 20 + kp] = val;
            }
        }
        __syncthreads();

        f32x4 sacc[2] = {{0.f,0.f,0.f,0.f},{0.f,0.f,0.f,0.f}};
#pragma unroll
        for (int u = 0; u < 8; ++u) {
            int nb = ((j8 << 3) + u) << 7;
            f16x8 Aw0[4], Aw1[4], Am[4];
#pragma unroll
            for (int ct = 0; ct < 4; ++ct) {
                Aw0[ct] = *(const f16x8*)&Ws[(ct * 16 + l15) * WS_S + q * 8];
                Aw1[ct] = *(const f16x8*)&Ws[(ct * 16 + l15) * WS_S + 32 + q * 8];
                Am[ct]  = *(const f16x8*)&Ms2[(ct * 16 + l15) * MS_S + q * 8];
            }
            f32x4 acc[4][2];
#pragma unroll
            for (int ct = 0; ct < 4; ++ct)
#pragma unroll
                for (int m = 0; m < 2; ++m) acc[ct][m] = (f32x4){0.f, 0.f, 0.f, 0.f};
#pragma unroll
            for (int mtl = 0; mtl < 2; ++mtl) {
                f16x8 B0, B1;
                HLOAD(u, mtl, B0, B1);
                f16x8 Bi = *(const f16x8*)&basI_g[(nb + 16 * (2 * wv + mtl) + l15) * 32 + q * 8];
#pragma unroll
                for (int ct = 0; ct < 4; ++ct) {
                    acc[ct][mtl] = __builtin_amdgcn_mfma_f32_16x16x32_f16(Aw0[ct], B0, acc[ct][mtl], 0, 0, 0);
                    acc[ct][mtl] = __builtin_amdgcn_mfma_f32_16x16x32_f16(Aw1[ct], B1, acc[ct][mtl], 0, 0, 0);
                    acc[ct][mtl] = __builtin_amdgcn_mfma_f32_16x16x32_f16(Am[ct],  Bi, acc[ct][mtl], 0, 0, 0);
                }
            }
            if (l < 3) {
#pragma unroll
                for (int mtl = 0; mtl < 2; ++mtl)
#pragma unroll
                    for (int ct = 0; ct < 4; ++ct) {
                        float g0 = gelu_t(acc[ct][mtl][0] + bls[ct * 16 + 4 * q + 0]);
                        float g1 = gelu_t(acc[ct][mtl][1] + bls[ct * 16 + 4 * q + 1]);
                        float g2 = gelu_t(acc[ct][mtl][2] + bls[ct * 16 + 4 * q + 2]);
                        float g3 = gelu_t(acc[ct][mtl][3] + bls[ct * 16 + 4 * q + 3]);
                        u32 pk0 = __builtin_bit_cast(u32, __builtin_amdgcn_cvt_pkrtz(g0, g1));
                        u32 pk1 = __builtin_bit_cast(u32, __builtin_amdgcn_cvt_pkrtz(g2, g3));
                        HSTORE1(u, mtl, (ct & 1) * 4 + 2 * (ct >> 1) + 0, pk0);
                        HSTORE1(u, mtl, (ct & 1) * 4 + 2 * (ct >> 1) + 1, pk1);
                    }
                UNIT_TAIL(u);
            } else {
#pragma unroll
                for (int mtl = 0; mtl < 2; ++mtl) {
                    float partial = 0.f;
#pragma unroll
                    for (int ct = 0; ct < 4; ++ct)
#pragma unroll
                        for (int r = 0; r < 4; ++r)
                            partial += qls[ct * 16 + 4 * q + r] *
                                       gelu_t(acc[ct][mtl][r] + bls[ct * 16 + 4 * q + r]);
                    partial += __shfl_xor(partial, 16);
                    partial += __shfl_xor(partial, 32);
                    if (q == 0)
                        out[(b << 13) + nb + 16 * (2 * wv + mtl) + l15] = partial + qb;
                }
            }
        }
        if (l < 3) {
#pragma unroll
            for (int mt = 0; mt < 2; ++mt)
#pragma unroll
                for (int r = 0; r < 4; ++r)
                    atomicAdd(&S[(b * 32 + mt * 16 + 4 * q + r) * 64 + wv * 16 + l15],
                              sacc[mt][r]);
            // ---- grid barrier (S complete)
            bt += 512;
            __threadfence();
            __syncthreads();
            if (t == 0) {
                __hip_atomic_fetch_add(cnt, 1u, __ATOMIC_ACQ_REL, __HIP_MEMORY_SCOPE_AGENT);
                long it = 0;
                while (__hip_atomic_load(cnt, __ATOMIC_ACQUIRE, __HIP_MEMORY_SCOPE_AGENT) < bt
                       && it < (1L << 23)) { __builtin_amdgcn_s_sleep(2); ++it; }
            }
            __syncthreads();
            __threadfence();
        }
    }
}

// ---------------------------------------------------------------- launch
extern "C" void kernel_launch(void* const* d_in, const int* in_sizes, int n_in,
                              void* d_out, int out_size, void* d_ws, size_t ws_size,
                              hipStream_t stream) {
    const float* x     = (const float*)d_in[0];
    const float* p_w   = (const float*)d_in[1];
    const float* p_b   = (const float*)d_in[2];
    const float* sc_wr = (const float*)d_in[3];
    const float* sc_wi = (const float*)d_in[4];
    const float* w_w   = (const float*)d_in[5];
    const float* w_b   = (const float*)d_in[6];
    const float* q_w   = (const float*)d_in[7];
    const float* q_b   = (const float*)d_in[8];
    float* out = (float*)d_out;

    char* ws = (char*)d_ws;
    float* S    = (float*)ws;                      // 524,288 B
    f16*   Mph  = (f16*)(ws + 524288ull);          // 262,144 B
    f16*   basF = (f16*)(ws + 786432ull);          // 524,288 B
    f16*   basI = (f16*)(ws + 1310720ull);         // 524,288 B
    f16*   Whp  = (f16*)(ws + 1835008ull);         // 32,768 B
    unsigned int* cnt = (unsigned int*)(ws + 1867776ull);   // 128 B

    hipLaunchKernelGGL(fill_basis, dim3(NN / 256), dim3(256), 0, stream,
                       basF, basI, w_w, Whp);
    (void)hipMemsetAsync(S, 0, 524288, stream);
    (void)hipMemsetAsync(cnt, 0, 128, stream);
    hipLaunchKernelGGL(fno_all, dim3(512), dim3(256), 0, stream,
                       x, p_w, p_b, Whp, w_b, sc_wr, sc_wi, q_w, q_b,
                       basF, basI, S, Mph, out, cnt);
}

// Round 10
// 1524.538 us; speedup vs baseline: 1.1619x; 1.0086x over previous
//
#include <hip/hip_runtime.h>
#include <math.h>

// FNO1d persistent kernel, R10 (= R9 + missing semicolons in FOR_RU6).
// Verified algorithm (R7/R8): pi-permuted B-layout h, identity-MFMA transpose,
// software grid barrier, tanh-GELU, 2 h-units in LDS. The 6 register-resident
// h units are 48 individually named u32x2 variables (token-pasted macros,
// fully macro-expanded unit code) so the allocator cannot bulk-spill an
// indexed aggregate; conv loop is ct-outer to cap peak pressure.

typedef _Float16 f16;
typedef _Float16 f16x8 __attribute__((ext_vector_type(8)));
typedef float    f32x4 __attribute__((ext_vector_type(4)));
typedef unsigned int u32;
typedef u32 u32x2 __attribute__((ext_vector_type(2)));
typedef u32 u32x4 __attribute__((ext_vector_type(4)));

#define NN 8192
#define HO_S 136   // Hout [o=64][n=128] halfs
#define WS_S 72    // Ws [o=64][s=64]
#define MS_S 40    // Ms2 [o=64][j=32]

__device__ __forceinline__ float gelu_t(float v) {
    float v2 = v * v;
    float y  = v * fmaf(v2, 0.0713548162f, 1.5957691216f);
    float e  = __expf(y);
    float r  = __builtin_amdgcn_rcpf(e + 1.0f);
    return fmaf(-v, r, v);   // inf-safe tanh-GELU
}

// ---------------------------------------------------------------- prep
__global__ __launch_bounds__(256) void fill_basis(f16* __restrict__ basF,
                                                  f16* __restrict__ basI,
                                                  const float* __restrict__ w_w,
                                                  f16* __restrict__ Whp) {
    int n = blockIdx.x * 256 + threadIdx.x;
    f16 row[32];
#pragma unroll
    for (int k = 0; k < 16; ++k) {
        float s, c;
        sincospif((float)(k * n) * (1.0f / 4096.0f), &s, &c);
        basF[k * NN + n]        = (f16)c;
        basF[(16 + k) * NN + n] = (f16)(-s);
        row[2 * k]     = (f16)c;
        row[2 * k + 1] = (f16)s;
    }
#pragma unroll
    for (int qq = 0; qq < 4; ++qq) *(f16x8*)&basI[n * 32 + 8 * qq] = *(f16x8*)&row[8 * qq];
#pragma unroll
    for (int rep = 0; rep < 2; ++rep) {
        int idx = n + rep * 8192;
        int l = idx >> 12, o = (idx >> 6) & 63, s = idx & 63;
        int ks = s >> 5, qq = (s >> 3) & 3, tt = (s >> 1) & 3, e = s & 1;
        int i = 32 * (tt >> 1) + 16 * ks + 4 * qq + 2 * (tt & 1) + e;   // pi(s)
        Whp[idx] = (f16)w_w[(l * 64 + o) * 64 + i];
    }
}

// ---- named h-state machinery -------------------------------------------
#define HNAME_(U, M, Q) h##U##_##M##_##Q
#define HNAME(U, M, Q) HNAME_(U, M, Q)

#define HDECL(U) u32x2 HNAME(U,0,0), HNAME(U,0,1), HNAME(U,0,2), HNAME(U,0,3), \
                       HNAME(U,1,0), HNAME(U,1,1), HNAME(U,1,2), HNAME(U,1,3)

#define HB0(U, M) __builtin_bit_cast(f16x8, (u32x4){HNAME(U,M,0)[0], HNAME(U,M,0)[1], \
                                                    HNAME(U,M,1)[0], HNAME(U,M,1)[1]})
#define HB1(U, M) __builtin_bit_cast(f16x8, (u32x4){HNAME(U,M,2)[0], HNAME(U,M,2)[1], \
                                                    HNAME(U,M,3)[0], HNAME(U,M,3)[1]})

#define HWR(U) do {                                                           \
    HNAME(U,0,0) = (u32x2){pks[0][0], pks[0][1]};                             \
    HNAME(U,0,1) = (u32x2){pks[0][2], pks[0][3]};                             \
    HNAME(U,0,2) = (u32x2){pks[0][4], pks[0][5]};                             \
    HNAME(U,0,3) = (u32x2){pks[0][6], pks[0][7]};                             \
    HNAME(U,1,0) = (u32x2){pks[1][0], pks[1][1]};                             \
    HNAME(U,1,1) = (u32x2){pks[1][2], pks[1][3]};                             \
    HNAME(U,1,2) = (u32x2){pks[1][4], pks[1][5]};                             \
    HNAME(U,1,3) = (u32x2){pks[1][6], pks[1][7]};                             \
} while (0)

#define FOR_RU6(X) X(0); X(1); X(2); X(3); X(4); X(5);

// LDS h units (u = 6,7), lane-stride-1, private per thread (verified R8)
#define HLDS_LOAD(u, mtl, B0v, B1v) do {                                      \
    u32 w_[8];                                                                \
    _Pragma("unroll")                                                         \
    for (int s_ = 0; s_ < 8; ++s_)                                            \
        w_[s_] = hlds[(((mtl) * 8 + s_) * 2 + (u) - 6) * 256 + t];            \
    B0v = __builtin_bit_cast(f16x8, (u32x4){w_[0], w_[1], w_[2], w_[3]});     \
    B1v = __builtin_bit_cast(f16x8, (u32x4){w_[4], w_[5], w_[6], w_[7]});     \
} while (0)

// transpose (identity MFMA) -> Hout[o][n], then DFT accumulate into sacc
#define TAIL_CORE(B0m0, B1m0, B0m1, B1m1, NB) do {                            \
    __syncthreads();                                                          \
    _Pragma("unroll")                                                         \
    for (int mtl_ = 0; mtl_ < 2; ++mtl_) {                                    \
        f16x8 Ba_ = mtl_ ? (B0m1) : (B0m0);                                   \
        f16x8 Bb_ = mtl_ ? (B1m1) : (B1m0);                                   \
        _Pragma("unroll")                                                     \
        for (int f_ = 0; f_ < 4; ++f_) {                                      \
            f32x4 d2_ = __builtin_amdgcn_mfma_f32_16x16x32_f16(               \
                (f_ & 1) ? Bb_ : Ba_, (f_ >> 1) ? Ehi : Elo,                  \
                (f32x4){0.f, 0.f, 0.f, 0.f}, 0, 0, 0);                        \
            u32 p0_ = __builtin_bit_cast(u32,                                 \
                __builtin_amdgcn_cvt_pkrtz(d2_[0], d2_[1]));                  \
            u32 p1_ = __builtin_bit_cast(u32,                                 \
                __builtin_amdgcn_cvt_pkrtz(d2_[2], d2_[3]));                  \
            u32x2 pr_ = {p0_, p1_};                                           \
            *(u32x2*)&Hout[(16 * f_ + l15) * HO_S + 16 * (2 * wv + mtl_) + 4 * q] = pr_; \
        }                                                                     \
    }                                                                         \
    __syncthreads();                                                          \
    _Pragma("unroll")                                                         \
    for (int ksn_ = 0; ksn_ < 4; ++ksn_) {                                    \
        f16x8 bh_ = *(const f16x8*)&Hout[(wv * 16 + l15) * HO_S + ksn_ * 32 + q * 8]; \
        _Pragma("unroll")                                                     \
        for (int mt_ = 0; mt_ < 2; ++mt_) {                                   \
            f16x8 af_ = *(const f16x8*)&basF_g[(mt_ * 16 + l15) * NN + (NB) + ksn_ * 32 + q * 8]; \
            sacc[mt_] = __builtin_amdgcn_mfma_f32_16x16x32_f16(af_, bh_, sacc[mt_], 0, 0, 0); \
        }                                                                     \
    }                                                                         \
} while (0)

#define TAIL_U(U) TAIL_CORE(HB0(U,0), HB1(U,0), HB0(U,1), HB1(U,1), (((j8 << 3) + (U)) << 7))

#define LIFT_U(U) do {                                                        \
    int nb_ = ((j8 << 3) + (U)) << 7;                                         \
    _Pragma("unroll")                                                         \
    for (int mtl_ = 0; mtl_ < 2; ++mtl_) {                                    \
        int n_ = nb_ + 16 * (2 * wv + mtl_) + l15;                            \
        float xv_ = x[(b << 13) + n_];                                        \
        float gr_ = (float)n_ * (1.0f / 8191.0f);                             \
        _Pragma("unroll")                                                     \
        for (int f_ = 0; f_ < 4; ++f_)                                        \
            _Pragma("unroll")                                                 \
            for (int g2_ = 0; g2_ < 2; ++g2_) {                               \
                int c_ = f_ * 4 + g2_ * 2;                                    \
                float v0_ = fmaf(pwA[c_], xv_, fmaf(pwB[c_], gr_, pbv[c_]));  \
                float v1_ = fmaf(pwA[c_ + 1], xv_, fmaf(pwB[c_ + 1], gr_, pbv[c_ + 1])); \
                pks[mtl_][(f_ & 1) * 4 + 2 * (f_ >> 1) + g2_] =               \
                    __builtin_bit_cast(u32, __builtin_amdgcn_cvt_pkrtz(v0_, v1_)); \
            }                                                                 \
    }                                                                         \
    HWR(U);                                                                   \
} while (0)

// conv+irfft MFMA core: fills acc[4][2]; ct-outer to cap A-frag liveness
#define CONV_CORE(B0m0, B1m0, B0m1, B1m1, NB) do {                            \
    f16x8 Bi0_ = *(const f16x8*)&basI_g[((NB) + 16 * (2 * wv + 0) + l15) * 32 + q * 8]; \
    f16x8 Bi1_ = *(const f16x8*)&basI_g[((NB) + 16 * (2 * wv + 1) + l15) * 32 + q * 8]; \
    _Pragma("unroll")                                                         \
    for (int ct_ = 0; ct_ < 4; ++ct_) {                                       \
        f16x8 Aw0_ = *(const f16x8*)&Ws[(ct_ * 16 + l15) * WS_S + q * 8];     \
        f16x8 Aw1_ = *(const f16x8*)&Ws[(ct_ * 16 + l15) * WS_S + 32 + q * 8]; \
        f16x8 Am_  = *(const f16x8*)&Ms2[(ct_ * 16 + l15) * MS_S + q * 8];    \
        acc[ct_][0] = (f32x4){0.f, 0.f, 0.f, 0.f};                            \
        acc[ct_][1] = (f32x4){0.f, 0.f, 0.f, 0.f};                            \
        acc[ct_][0] = __builtin_amdgcn_mfma_f32_16x16x32_f16(Aw0_, B0m0, acc[ct_][0], 0, 0, 0); \
        acc[ct_][0] = __builtin_amdgcn_mfma_f32_16x16x32_f16(Aw1_, B1m0, acc[ct_][0], 0, 0, 0); \
        acc[ct_][0] = __builtin_amdgcn_mfma_f32_16x16x32_f16(Am_,  Bi0_, acc[ct_][0], 0, 0, 0); \
        acc[ct_][1] = __builtin_amdgcn_mfma_f32_16x16x32_f16(Aw0_, B0m1, acc[ct_][1], 0, 0, 0); \
        acc[ct_][1] = __builtin_amdgcn_mfma_f32_16x16x32_f16(Aw1_, B1m1, acc[ct_][1], 0, 0, 0); \
        acc[ct_][1] = __builtin_amdgcn_mfma_f32_16x16x32_f16(Am_,  Bi1_, acc[ct_][1], 0, 0, 0); \
    }                                                                         \
} while (0)

#define GELU_PKS() do {                                                       \
    _Pragma("unroll")                                                         \
    for (int mtl_ = 0; mtl_ < 2; ++mtl_)                                      \
        _Pragma("unroll")                                                     \
        for (int ct_ = 0; ct_ < 4; ++ct_) {                                   \
            float g0_ = gelu_t(acc[ct_][mtl_][0] + bls[ct_ * 16 + 4 * q + 0]); \
            float g1_ = gelu_t(acc[ct_][mtl_][1] + bls[ct_ * 16 + 4 * q + 1]); \
            float g2_ = gelu_t(acc[ct_][mtl_][2] + bls[ct_ * 16 + 4 * q + 2]); \
            float g3_ = gelu_t(acc[ct_][mtl_][3] + bls[ct_ * 16 + 4 * q + 3]); \
            int base_ = (ct_ & 1) * 4 + 2 * (ct_ >> 1);                       \
            pks[mtl_][base_]     = __builtin_bit_cast(u32, __builtin_amdgcn_cvt_pkrtz(g0_, g1_)); \
            pks[mtl_][base_ + 1] = __builtin_bit_cast(u32, __builtin_amdgcn_cvt_pkrtz(g2_, g3_)); \
        }                                                                     \
} while (0)

#define PROJ_OUT(NB) do {                                                     \
    _Pragma("unroll")                                                         \
    for (int mtl_ = 0; mtl_ < 2; ++mtl_) {                                    \
        float partial_ = 0.f;                                                 \
        _Pragma("unroll")                                                     \
        for (int ct_ = 0; ct_ < 4; ++ct_)                                     \
            _Pragma("unroll")                                                 \
            for (int r_ = 0; r_ < 4; ++r_)                                    \
                partial_ += qls[ct_ * 16 + 4 * q + r_] *                      \
                            gelu_t(acc[ct_][mtl_][r_] + bls[ct_ * 16 + 4 * q + r_]); \
        partial_ += __shfl_xor(partial_, 16);                                 \
        partial_ += __shfl_xor(partial_, 32);                                 \
        if (q == 0)                                                           \
            out[(b << 13) + (NB) + 16 * (2 * wv + mtl_) + l15] = partial_ + qb; \
    }                                                                         \
} while (0)

#define CONV_U(U) do {                                                        \
    int nbu_ = ((j8 << 3) + (U)) << 7;                                        \
    f32x4 acc[4][2];                                                          \
    {                                                                         \
        f16x8 Bq0_ = HB0(U,0), Bq1_ = HB1(U,0), Bq2_ = HB0(U,1), Bq3_ = HB1(U,1); \
        CONV_CORE(Bq0_, Bq1_, Bq2_, Bq3_, nbu_);                              \
    }                                                                         \
    if (l < 3) {                                                              \
        u32 pks[2][8];                                                        \
        GELU_PKS();                                                           \
        HWR(U);                                                               \
        TAIL_U(U);                                                            \
    } else {                                                                  \
        PROJ_OUT(nbu_);                                                       \
    }                                                                         \
} while (0)

#define GBAR() do {                                                           \
    bt += 512;                                                                \
    __threadfence();                                                          \
    __syncthreads();                                                          \
    if (t == 0) {                                                             \
        __hip_atomic_fetch_add(cnt, 1u, __ATOMIC_ACQ_REL, __HIP_MEMORY_SCOPE_AGENT); \
        long it_ = 0;                                                         \
        while (__hip_atomic_load(cnt, __ATOMIC_ACQUIRE, __HIP_MEMORY_SCOPE_AGENT) < bt \
               && it_ < (1L << 23)) { __builtin_amdgcn_s_sleep(2); ++it_; }   \
    }                                                                         \
    __syncthreads();                                                          \
    __threadfence();                                                          \
} while (0)

// ---------------------------------------------------------------- main
__global__ __launch_bounds__(256, 2) void fno_all(
    const float* __restrict__ x, const float* __restrict__ p_w,
    const float* __restrict__ p_b, const f16* __restrict__ Whp,
    const float* __restrict__ w_b, const float* __restrict__ sc_wr,
    const float* __restrict__ sc_wi, const float* __restrict__ q_w,
    const float* __restrict__ q_b, const f16* __restrict__ basF_g,
    const f16* __restrict__ basI_g, float* __restrict__ S,
    f16* __restrict__ Mph, float* __restrict__ out,
    unsigned int* __restrict__ cnt) {
    __shared__ __align__(16) char poolA[64 * HO_S * 2];   // Hout / modemix Ss
    __shared__ __align__(16) f16 Ws[64 * WS_S];
    __shared__ __align__(16) f16 Ms2[64 * MS_S];
    __shared__ u32 hlds[2 * 256 * 16];                    // 32768 B: h units 6,7
    __shared__ float bls[64];
    __shared__ float qls[64];
    f16* Hout = (f16*)poolA;
    float* Ss = (float*)poolA;

    const int t = threadIdx.x, g = blockIdx.x;
    const int b = g >> 3, j8 = g & 7;
    const int lane = t & 63, wv = t >> 6, q = lane >> 4, l15 = lane & 15;

    f16x8 Elo = {0, 0, 0, 0, 0, 0, 0, 0};
    f16x8 Ehi = {0, 0, 0, 0, 0, 0, 0, 0};
    {
        int d = l15 - 4 * q;
#pragma unroll
        for (int j = 0; j < 4; ++j)
            if (j == d) { Elo[j] = (f16)1; Ehi[j + 4] = (f16)1; }
    }

    if (t < 64) qls[t] = q_w[t];
    float qb = q_b[0];

    FOR_RU6(HDECL);
    unsigned bt = 0;

    // ================= lift into h (pi-packed B layout) =================
    {
        float pwA[16], pwB[16], pbv[16];
#pragma unroll
        for (int f = 0; f < 4; ++f)
#pragma unroll
            for (int g2 = 0; g2 < 2; ++g2)
#pragma unroll
                for (int e = 0; e < 2; ++e) {
                    int c = f * 4 + g2 * 2 + e;
                    int i = 16 * f + 4 * q + 2 * g2 + e;
                    pwA[c] = p_w[2 * i]; pwB[c] = p_w[2 * i + 1]; pbv[c] = p_b[i];
                }
        u32 pks[2][8];
        FOR_RU6(LIFT_U);
        for (int u = 6; u < 8; ++u) {
            int nb_ = ((j8 << 3) + u) << 7;
#pragma unroll
            for (int mtl_ = 0; mtl_ < 2; ++mtl_) {
                int n_ = nb_ + 16 * (2 * wv + mtl_) + l15;
                float xv_ = x[(b << 13) + n_];
                float gr_ = (float)n_ * (1.0f / 8191.0f);
#pragma unroll
                for (int f_ = 0; f_ < 4; ++f_)
#pragma unroll
                    for (int g2_ = 0; g2_ < 2; ++g2_) {
                        int c_ = f_ * 4 + g2_ * 2;
                        float v0_ = fmaf(pwA[c_], xv_, fmaf(pwB[c_], gr_, pbv[c_]));
                        float v1_ = fmaf(pwA[c_ + 1], xv_, fmaf(pwB[c_ + 1], gr_, pbv[c_ + 1]));
                        hlds[(((mtl_) * 8 + ((f_ & 1) * 4 + 2 * (f_ >> 1) + g2_)) * 2 + u - 6) * 256 + t] =
                            __builtin_bit_cast(u32, __builtin_amdgcn_cvt_pkrtz(v0_, v1_));
                    }
            }
        }
    }
    {
        f32x4 sacc[2] = {{0.f,0.f,0.f,0.f},{0.f,0.f,0.f,0.f}};
        FOR_RU6(TAIL_U);
        for (int u = 6; u < 8; ++u) {
            f16x8 L0m0, L1m0, L0m1, L1m1;
            HLDS_LOAD(u, 0, L0m0, L1m0);
            HLDS_LOAD(u, 1, L0m1, L1m1);
            TAIL_CORE(L0m0, L1m0, L0m1, L1m1, ((j8 << 3) + u) << 7);
        }
#pragma unroll
        for (int mt = 0; mt < 2; ++mt)
#pragma unroll
            for (int r = 0; r < 4; ++r)
                atomicAdd(&S[(b * 32 + mt * 16 + 4 * q + r) * 64 + wv * 16 + l15],
                          sacc[mt][r]);
    }
    GBAR();

    // ================= layers =================
    for (int l = 0; l < 4; ++l) {
#pragma unroll
        for (int rr = 0; rr < 2; ++rr) {
            int v = t + 256 * rr;
            int o = v >> 3, c = (v & 7) * 8;
            *(f16x8*)&Ws[o * WS_S + c] = *(const f16x8*)&Whp[l * 4096 + o * 64 + c];
        }
        if (t < 64) bls[t] = w_b[l * 64 + t];
        if (j8 == 0) {
            // modemix for this b (agent-scope for XCD coherence)
#pragma unroll
            for (int r = 0; r < 8; ++r) {
                int v = t + 256 * r;
                Ss[(v >> 6) * 66 + (v & 63)] =
                    __hip_atomic_load(&S[b * 2048 + v], __ATOMIC_RELAXED,
                                      __HIP_MEMORY_SCOPE_AGENT);
            }
            __syncthreads();
            const float* wr = sc_wr + l * 65536;
            const float* wi = sc_wi + l * 65536;
            u32* MphU = (u32*)Mph;
#pragma unroll
            for (int it2 = 0; it2 < 4; ++it2) {
                int p = it2 * 256 + t;     // o*16+k
                int o = p >> 4, k = p & 15;
                float ar = 0.f, ai = 0.f;
#pragma unroll 4
                for (int i = 0; i < 64; ++i) {
                    float sr = Ss[k * 66 + i], si = Ss[(16 + k) * 66 + i];
                    float wrv = wr[(i * 64 + o) * 16 + k];
                    float wiv = wi[(i * 64 + o) * 16 + k];
                    ar += sr * wrv - si * wiv;
                    ai += sr * wiv + si * wrv;
                }
                float sc = (k == 0 ? 1.0f : 2.0f) * (1.0f / 8192.0f);
                u32 pk = __builtin_bit_cast(u32,
                    __builtin_amdgcn_cvt_pkrtz(sc * ar, -sc * ai));
                __hip_atomic_store(&MphU[b * 1024 + o * 16 + k], pk,
                                   __ATOMIC_RELAXED, __HIP_MEMORY_SCOPE_AGENT);
            }
#pragma unroll
            for (int r = 0; r < 8; ++r)
                __hip_atomic_store(&S[b * 2048 + t + 256 * r], 0.f,
                                   __ATOMIC_RELAXED, __HIP_MEMORY_SCOPE_AGENT);
        }
        GBAR();   // Mph ready, S zeroed
        {
            u32* Ms2U = (u32*)Ms2;
            const u32* MphU = (const u32*)Mph;
#pragma unroll
            for (int ii = 0; ii < 4; ++ii) {
                int idx = ii * 256 + t;
                int o = idx >> 4, kp = idx & 15;
                u32 val = __hip_atomic_load(&MphU[b * 1024 + idx], __ATOMIC_RELAXED,
                                            __HIP_MEMORY_SCOPE_AGENT);
                Ms2U[o * 20 + kp] = val;
            }
        }
        __syncthreads();

        f32x4 sacc[2] = {{0.f,0.f,0.f,0.f},{0.f,0.f,0.f,0.f}};
        FOR_RU6(CONV_U);
        for (int u = 6; u < 8; ++u) {
            int nbu = ((j8 << 3) + u) << 7;
            f32x4 acc[4][2];
            {
                f16x8 L0m0, L1m0, L0m1, L1m1;
                HLDS_LOAD(u, 0, L0m0, L1m0);
                HLDS_LOAD(u, 1, L0m1, L1m1);
                CONV_CORE(L0m0, L1m0, L0m1, L1m1, nbu);
            }
            if (l < 3) {
                u32 pks[2][8];
                GELU_PKS();
#pragma unroll
                for (int mtl_ = 0; mtl_ < 2; ++mtl_)
#pragma unroll
                    for (int s_ = 0; s_ < 8; ++s_)
                        hlds[((mtl_ * 8 + s_) * 2 + u - 6) * 256 + t] = pks[mtl_][s_];
                {
                    f16x8 L0m0, L1m0, L0m1, L1m1;
                    HLDS_LOAD(u, 0, L0m0, L1m0);
                    HLDS_LOAD(u, 1, L0m1, L1m1);
                    TAIL_CORE(L0m0, L1m0, L0m1, L1m1, nbu);
                }
            } else {
                PROJ_OUT(nbu);
            }
        }
        if (l < 3) {
#pragma unroll
            for (int mt = 0; mt < 2; ++mt)
#pragma unroll
                for (int r = 0; r < 4; ++r)
                    atomicAdd(&S[(b * 32 + mt * 16 + 4 * q + r) * 64 + wv * 16 + l15],
                              sacc[mt][r]);
            GBAR();   // S complete
        }
    }
}

// ---------------------------------------------------------------- launch
extern "C" void kernel_launch(void* const* d_in, const int* in_sizes, int n_in,
                              void* d_out, int out_size, void* d_ws, size_t ws_size,
                              hipStream_t stream) {
    const float* x     = (const float*)d_in[0];
    const float* p_w   = (const float*)d_in[1];
    const float* p_b   = (const float*)d_in[2];
    const float* sc_wr = (const float*)d_in[3];
    const float* sc_wi = (const float*)d_in[4];
    const float* w_w   = (const float*)d_in[5];
    const float* w_b   = (const float*)d_in[6];
    const float* q_w   = (const float*)d_in[7];
    const float* q_b   = (const float*)d_in[8];
    float* out = (float*)d_out;

    char* ws = (char*)d_ws;
    float* S    = (float*)ws;                      // 524,288 B
    f16*   Mph  = (f16*)(ws + 524288ull);          // 262,144 B
    f16*   basF = (f16*)(ws + 786432ull);          // 524,288 B
    f16*   basI = (f16*)(ws + 1310720ull);         // 524,288 B
    f16*   Whp  = (f16*)(ws + 1835008ull);         // 32,768 B
    unsigned int* cnt = (unsigned int*)(ws + 1867776ull);   // 128 B

    hipLaunchKernelGGL(fill_basis, dim3(NN / 256), dim3(256), 0, stream,
                       basF, basI, w_w, Whp);
    (void)hipMemsetAsync(S, 0, 524288, stream);
    (void)hipMemsetAsync(cnt, 0, 128, stream);
    hipLaunchKernelGGL(fno_all, dim3(512), dim3(256), 0, stream,
                       x, p_w, p_b, Whp, w_b, sc_wr, sc_wi, q_w, q_b,
                       basF, basI, S, Mph, out, cnt);
}